// Round 6
// baseline (504.105 us; speedup 1.0000x reference)
//
#include <hip/hip_runtime.h>

#define MAXNB 1024  // max dst-buckets (128 nodes each) -> supports n <= 131072
#define NSLOT 8     // BN stats spread (contention vs redundant-read tradeoff)

typedef __attribute__((ext_vector_type(8))) short bf8;    // 8 bf16 (4 VGPRs)
typedef __attribute__((ext_vector_type(4))) float f32x4;  // MFMA C/D

// pack two fp32 -> two bf16 (RNE) in one uint (a = low = even channel)
__device__ __forceinline__ unsigned pack_bf16x2(float a, float b) {
  unsigned ua = __float_as_uint(a);
  ua = (ua + 0x7fffu + ((ua >> 16) & 1u)) >> 16;
  unsigned ub = __float_as_uint(b);
  ub = (ub + 0x7fffu + ((ub >> 16) & 1u)) >> 16;
  return ua | (ub << 16);
}

// ---- W prep: fp32 [128k][128c] -> bf16 B-fragments for 16x16x32 MFMA ------
// grid 16: blocks 0-7 -> W1/Wf1, blocks 8-15 -> W2/Wf2.
__global__ __launch_bounds__(256) void k_wprep(const float* __restrict__ W1,
                                               uint4* __restrict__ Wf1,
                                               const float* __restrict__ W2,
                                               uint4* __restrict__ Wf2) {
  const int half = blockIdx.x >> 3;
  const float* W = half ? W2 : W1;
  uint4* Wf = half ? Wf2 : Wf1;
  const int t = (blockIdx.x & 7) * 256 + threadIdx.x;  // 0..2047
  const int frag = t >> 6, lane = t & 63;
  const int ct = frag >> 2, kc = frag & 3;
  const int col = ct * 16 + (lane & 15);
  const int k0 = kc * 32 + (lane >> 4) * 8;
  unsigned p[4];
#pragma unroll
  for (int j = 0; j < 4; ++j)
    p[j] = pack_bf16x2(W[(k0 + 2 * j) * 128 + col],
                       W[(k0 + 2 * j + 1) * 128 + col]);
  Wf[t] = make_uint4(p[0], p[1], p[2], p[3]);
}

// ---- MFMA GEMM: H(bf16) = X[n,128] @ W[128,128], fused alpha dots ---------
// Hb output layout is PAIR-SHARDED: [pair][n][64ch] where pair p holds
// heads {2p,2p+1} (channels 64p..64p+63) as one 128B line per node.
// If stats!=null: inline BN-finalize and fold x = relu(x*sc+sh) into the
// A-fragment load.
__global__ __launch_bounds__(256) void k_gemm(
    const float* __restrict__ X, const uint4* __restrict__ Wf,
    unsigned* __restrict__ Hb, int n, const float* __restrict__ stats,
    const float* __restrict__ gamma, const float* __restrict__ beta,
    float invN, const float* __restrict__ a_src,
    const float* __restrict__ a_dst, float* __restrict__ as_,
    float* __restrict__ ad_) {
  __shared__ float stag[64 * 132];  // 33792 B
  __shared__ float ssl[256];        // BN scale/shift
  const int tid = threadIdx.x;
  if (stats && tid < 128) {
    float s = 0.f, s2 = 0.f;
#pragma unroll
    for (int k = 0; k < NSLOT; ++k) {
      s += stats[k * 256 + tid];
      s2 += stats[k * 256 + 128 + tid];
    }
    float mean = s * invN;
    float var = s2 * invN - mean * mean;
    float sc = gamma[tid] * rsqrtf(var + 1e-5f);
    ssl[tid] = sc;
    ssl[128 + tid] = beta[tid] - mean * sc;
  }
  __syncthreads();

  const int w = tid >> 6, lane = tid & 63;
  const int q = lane >> 4, nl = lane & 15;
  const long row0 = (long)blockIdx.x * 64;
  long rowA = row0 + w * 16 + nl;
  if (rowA >= n) rowA = n - 1;  // clamp; stores are guarded

  bf8 a[4];
#pragma unroll
  for (int kc = 0; kc < 4; ++kc) {
    const float* p = X + rowA * 128 + kc * 32 + q * 8;
    float4 v0 = *(const float4*)p;
    float4 v1 = *(const float4*)(p + 4);
    if (stats) {  // fold previous layer's BN+ReLU
      const int kb = kc * 32 + q * 8;
      float4 s0 = *(const float4*)&ssl[kb];
      float4 s1 = *(const float4*)&ssl[kb + 4];
      float4 h0 = *(const float4*)&ssl[128 + kb];
      float4 h1 = *(const float4*)&ssl[128 + kb + 4];
      v0.x = fmaxf(fmaf(v0.x, s0.x, h0.x), 0.f);
      v0.y = fmaxf(fmaf(v0.y, s0.y, h0.y), 0.f);
      v0.z = fmaxf(fmaf(v0.z, s0.z, h0.z), 0.f);
      v0.w = fmaxf(fmaf(v0.w, s0.w, h0.w), 0.f);
      v1.x = fmaxf(fmaf(v1.x, s1.x, h1.x), 0.f);
      v1.y = fmaxf(fmaf(v1.y, s1.y, h1.y), 0.f);
      v1.z = fmaxf(fmaf(v1.z, s1.z, h1.z), 0.f);
      v1.w = fmaxf(fmaf(v1.w, s1.w, h1.w), 0.f);
    }
    union { uint4 u; bf8 v; } cv;
    cv.u = make_uint4(pack_bf16x2(v0.x, v0.y), pack_bf16x2(v0.z, v0.w),
                      pack_bf16x2(v1.x, v1.y), pack_bf16x2(v1.z, v1.w));
    a[kc] = cv.v;
  }

  f32x4 acc[8];
#pragma unroll
  for (int ct = 0; ct < 8; ++ct) {
    f32x4 c = {0.f, 0.f, 0.f, 0.f};
#pragma unroll
    for (int kc = 0; kc < 4; ++kc) {
      union { uint4 u; bf8 v; } b;
      b.u = Wf[(ct * 4 + kc) * 64 + lane];
      c = __builtin_amdgcn_mfma_f32_16x16x32_bf16(a[kc], b.v, c, 0, 0, 0);
    }
    acc[ct] = c;
  }

  const int lr = w * 16 + q * 4;
#pragma unroll
  for (int ct = 0; ct < 8; ++ct)
#pragma unroll
    for (int r = 0; r < 4; ++r)
      stag[(lr + r) * 132 + ct * 16 + nl] = acc[ct][r];
  __syncthreads();

  {
    const int row = tid >> 2, seg = tid & 3;  // seg = head
    const long grow = row0 + row;
    if (grow < n) {
      float sp = 0.f, dp = 0.f;
      const float* p = &stag[row * 132 + seg * 32];
      // pair-sharded Hb: pair = seg>>1, half-line = seg&1
      uint2* HbO = (uint2*)Hb + (size_t)(seg >> 1) * n * 16;
      const long hb = grow * 16 + (seg & 1) * 8;
#pragma unroll
      for (int i = 0; i < 8; ++i) {
        float4 h4 = *(const float4*)(p + i * 4);
        float4 s4 = ((const float4*)a_src)[seg * 8 + i];
        float4 d4 = ((const float4*)a_dst)[seg * 8 + i];
        sp += h4.x * s4.x + h4.y * s4.y + h4.z * s4.z + h4.w * s4.w;
        dp += h4.x * d4.x + h4.y * d4.y + h4.z * d4.z + h4.w * d4.w;
        uint2 o;
        o.x = pack_bf16x2(h4.x, h4.y);
        o.y = pack_bf16x2(h4.z, h4.w);
        HbO[hb + i] = o;
      }
      as_[grow * 4 + seg] = sp;
      ad_[grow * 4 + seg] = dp;
    }
  }
}

// ---------------- CSR build via dst-bucket binning --------------------------
__global__ __launch_bounds__(256) void k_hist(const int* __restrict__ ei,
                                              int E, int NB,
                                              int* __restrict__ bcnt) {
  __shared__ int hist[MAXNB];
  for (int i = threadIdx.x; i < NB; i += 256) hist[i] = 0;
  __syncthreads();
  const int e0 = blockIdx.x * 4096;
#pragma unroll
  for (int k = 0; k < 16; ++k) {
    int e = e0 + k * 256 + threadIdx.x;
    if (e < E) atomicAdd(&hist[ei[E + e] >> 7], 1);
  }
  __syncthreads();
  for (int i = threadIdx.x; i < NB; i += 256) {
    int c = hist[i];
    if (c) atomicAdd(&bcnt[i], c);
  }
}

__global__ __launch_bounds__(1024) void k_bprefix(const int* __restrict__ bcnt,
                                                  int NB,
                                                  int* __restrict__ bstart,
                                                  int* __restrict__ bcur) {
  __shared__ int sh[1024];
  const int t = threadIdx.x;
  int v = (t < NB) ? bcnt[t] : 0;
  sh[t] = v;
  __syncthreads();
  for (int off = 1; off < 1024; off <<= 1) {
    int u = (t >= off) ? sh[t - off] : 0;
    __syncthreads();
    sh[t] += u;
    __syncthreads();
  }
  if (t < NB) {
    int ex = sh[t] - v;
    bstart[t] = ex;
    bcur[t] = ex;
    if (t == NB - 1) bstart[NB] = sh[t];
  }
}

__global__ __launch_bounds__(256) void k_scatter(const int* __restrict__ ei,
                                                 int E, int NB,
                                                 int* __restrict__ bcur,
                                                 int* __restrict__ packed) {
  __shared__ int hist[MAXNB];
  __shared__ int hbase[MAXNB];
  for (int i = threadIdx.x; i < NB; i += 256) hist[i] = 0;
  __syncthreads();
  const int e0 = blockIdx.x * 4096;
  int myb[16], myv[16];
#pragma unroll
  for (int k = 0; k < 16; ++k) {
    int e = e0 + k * 256 + threadIdx.x;
    myb[k] = -1;
    myv[k] = 0;
    if (e < E) {
      int s = ei[e], d = ei[E + e];
      myb[k] = d >> 7;
      myv[k] = (s << 7) | (d & 127);
      atomicAdd(&hist[myb[k]], 1);
    }
  }
  __syncthreads();
  for (int i = threadIdx.x; i < NB; i += 256) {
    int c = hist[i];
    hbase[i] = c ? atomicAdd(&bcur[i], c) : 0;
    hist[i] = 0;
  }
  __syncthreads();
#pragma unroll
  for (int k = 0; k < 16; ++k) {
    if (myb[k] >= 0) {
      int p = hbase[myb[k]] + atomicAdd(&hist[myb[k]], 1);
      packed[p] = myv[k];
    }
  }
}

__global__ __launch_bounds__(256) void k_local(const int* __restrict__ packed,
                                               const int* __restrict__ bstart,
                                               int n, int* __restrict__ srcs,
                                               int* __restrict__ offs,
                                               int* __restrict__ deg) {
  const int b = blockIdx.x;
  const int node0 = b << 7;
  const int nn = min(128, n - node0);
  const int e0 = bstart[b], e1 = bstart[b + 1];
  __shared__ int dcnt[128], cur[128], scan[128];
  const int tid = threadIdx.x;
  if (tid < 128) dcnt[tid] = 0;
  __syncthreads();
  for (int i = e0 + tid; i < e1; i += 256)
    atomicAdd(&dcnt[packed[i] & 127], 1);
  __syncthreads();
  int v = 0;
  if (tid < 128) {
    v = (tid < nn) ? dcnt[tid] + 1 : 0;  // +1 = self-loop slot
    scan[tid] = v;
  }
  __syncthreads();
  for (int off = 1; off < 128; off <<= 1) {
    int u = 0;
    if (tid < 128 && tid >= off) u = scan[tid - off];
    __syncthreads();
    if (tid < 128) scan[tid] += u;
    __syncthreads();
  }
  if (tid < nn) {
    const int o = e0 + node0 + (scan[tid] - v);  // global CSR offset
    offs[node0 + tid] = o;
    deg[node0 + tid] = dcnt[tid];
    srcs[o] = node0 + tid;  // self-loop first
    cur[tid] = o + 1;
  }
  __syncthreads();
  for (int i = e0 + tid; i < e1; i += 256) {
    const int pv = packed[i];
    const int p = atomicAdd(&cur[pv & 127], 1);
    srcs[p] = pv >> 7;
  }
}

// ---------------- fused GAT aggregation + BN-stats accumulation -------------
// HEAD-PAIR-SHARDED + HW-XCC-PINNED.
// Hb is [2][n][128B]: pair p = heads {2p,2p+1}. Each block processes 32 nodes
// for ONE pair: 8 lanes/node read exactly one 128B TCC line per edge (no
// granularity waste — round-3 lesson). Blocks claim tiles from a per-pair
// atomic queue keyed on the HARDWARE XCC_ID (s_getreg, measured m09) —
// XCDs {odd} serve pair 1, {even} pair 0 — so each XCD's L2 only holds a
// 12.8 MB slice: replication floor ~180MB -> ~90MB. Exact-fill stealing
// guarantees every tile is processed exactly once regardless of how the
// dispatcher spreads blocks over XCDs. Pipeline: r1-style compiler-scheduled
// 1-chunk logit lookahead (r2/r4/r5: forcing depth costs occupancy/spill).
__global__ __launch_bounds__(256) void k_agg(
    const int* __restrict__ offs, const int* __restrict__ deg,
    const int* __restrict__ srcs, const uint4* __restrict__ Hb,
    const float* __restrict__ as_, const float* __restrict__ ad_,
    float* __restrict__ out, float* __restrict__ stats, int n, int ntiles,
    int* __restrict__ qctr) {
  __shared__ float sblk[4][2][64];
  __shared__ int shp, sht;
  const int tid = threadIdx.x;
  if (tid == 0) {
    int xcc;
    asm volatile("s_getreg_b32 %0, hwreg(HW_REG_XCC_ID)" : "=s"(xcc));
    int p = xcc & 1;
    int t = atomicAdd(&qctr[p], 1);
    if (t >= ntiles) {  // my pair's tiles exhausted -> steal (exact fill)
      p ^= 1;
      t = atomicAdd(&qctr[p], 1);
    }
    shp = p;
    sht = t;
  }
  __syncthreads();
  const int pair = shp;
  const int tile = sht;
  if (tile >= ntiles) return;  // unreachable by exact-fill; uniform guard

  const int w = tid >> 6, lane = tid & 63;
  const int t8 = lane & 7;  // 16B slice of the 128B pair line; also edge slot
  const int hsel = lane & 4;  // head within pair for my channels
  const int node = tile * 32 + (tid >> 3);
  const bool active = node < n;
  const int o0 = active ? offs[node] : 0;
  const int dg = active ? deg[node] + 1 : 0;  // + self-loop
  float2 advp = make_float2(0.f, 0.f);
  if (active) advp = *(const float2*)&ad_[node * 4 + pair * 2];
  const int* sp = srcs + o0;
  const uint4* Hp = Hb + (size_t)pair * n * 8 + t8;  // line = 8 uint4
  const float* asP = as_ + pair * 2;

  float den = 0.f;
  float acc[8];
#pragma unroll
  for (int i = 0; i < 8; ++i) acc[i] = 0.f;

// load slot J's (src, exp-weights for BOTH heads of the pair); index clamped
// to the self-loop slot so loads are unconditional; weights zeroed for pads.
#define LOADSE(J, S, E0, E1)                            \
  {                                                     \
    const int j_ = (J);                                 \
    S = sp[j_ < dg ? j_ : 0];                           \
    float2 a2_ = *(const float2*)&asP[S * 4];           \
    float l0_ = a2_.x + advp.x;                         \
    l0_ = l0_ >= 0.f ? l0_ : 0.2f * l0_;                \
    float l1_ = a2_.y + advp.y;                         \
    l1_ = l1_ >= 0.f ? l1_ : 0.2f * l1_;                \
    E0 = (j_ < dg) ? __expf(fminf(l0_, 80.f)) : 0.f;    \
    E1 = (j_ < dg) ? __expf(fminf(l1_, 80.f)) : 0.f;    \
  }

// process slot JJ: broadcast src + both weights within the 8-lane node
// group (BitMode: src_lane = (lane & 0x18) | JJ), gather the 128B line,
// select my head's weight, accumulate.
#define DOSLOT(JJ)                                                         \
  {                                                                        \
    int ss_ = __builtin_amdgcn_ds_swizzle(s_c, ((JJ) << 5) | 0x18);        \
    float w0_ = __uint_as_float(__builtin_amdgcn_ds_swizzle(               \
        __float_as_int(e0c), ((JJ) << 5) | 0x18));                         \
    float w1_ = __uint_as_float(__builtin_amdgcn_ds_swizzle(               \
        __float_as_int(e1c), ((JJ) << 5) | 0x18));                         \
    const float wv_ = hsel ? w1_ : w0_;                                    \
    const uint4 hv = Hp[(long)ss_ * 8];                                    \
    den += wv_;                                                            \
    acc[0] = fmaf(wv_, __uint_as_float(hv.x << 16), acc[0]);               \
    acc[1] = fmaf(wv_, __uint_as_float(hv.x & 0xffff0000u), acc[1]);       \
    acc[2] = fmaf(wv_, __uint_as_float(hv.y << 16), acc[2]);               \
    acc[3] = fmaf(wv_, __uint_as_float(hv.y & 0xffff0000u), acc[3]);       \
    acc[4] = fmaf(wv_, __uint_as_float(hv.z << 16), acc[4]);               \
    acc[5] = fmaf(wv_, __uint_as_float(hv.z & 0xffff0000u), acc[5]);       \
    acc[6] = fmaf(wv_, __uint_as_float(hv.w << 16), acc[6]);               \
    acc[7] = fmaf(wv_, __uint_as_float(hv.w & 0xffff0000u), acc[7]);       \
  }

  int s_c, s_n;
  float e0c, e1c, e0n, e1n;
  LOADSE(t8, s_c, e0c, e1c);

  for (int base = 0; base < dg; base += 8) {
    LOADSE(base + 8 + t8, s_n, e0n, e1n);
    DOSLOT(0);
    DOSLOT(1);
    DOSLOT(2);
    DOSLOT(3);
    DOSLOT(4);
    DOSLOT(5);
    DOSLOT(6);
    DOSLOT(7);
    s_c = s_n;
    e0c = e0n;
    e1c = e1n;
  }
#undef LOADSE
#undef DOSLOT

  // den is already uniform across the 4-lane head subgroup (every lane
  // accumulated every slot's broadcast weight).
  const float invden = 1.f / (den + 1e-16f);
  float sums[8], sqs[8];
#pragma unroll
  for (int i = 0; i < 8; ++i) {
    float v = acc[i] * invden;
    acc[i] = v;
    sums[i] = v;
    sqs[i] = v * v;
  }
  if (active) {
    float4 o0v = make_float4(acc[0], acc[1], acc[2], acc[3]);
    float4 o1v = make_float4(acc[4], acc[5], acc[6], acc[7]);
    ((float4*)out)[(long)node * 32 + pair * 16 + t8 * 2] = o0v;
    ((float4*)out)[(long)node * 32 + pair * 16 + t8 * 2 + 1] = o1v;
  }
  // reduce over the wave's 8 nodes (lane bits 3,4,5); bits 0..2 = channels
#pragma unroll
  for (int off = 8; off <= 32; off <<= 1) {
#pragma unroll
    for (int i = 0; i < 8; ++i) {
      sums[i] += __shfl_xor(sums[i], off, 64);
      sqs[i] += __shfl_xor(sqs[i], off, 64);
    }
  }
  if (lane < 8) {
#pragma unroll
    for (int i = 0; i < 8; ++i) {
      sblk[w][0][lane * 8 + i] = sums[i];
      sblk[w][1][lane * 8 + i] = sqs[i];
    }
  }
  __syncthreads();
  if (tid < 128) {
    const int c = tid & 63, sidx = tid >> 6;
    float v = sblk[0][sidx][c] + sblk[1][sidx][c] + sblk[2][sidx][c] +
              sblk[3][sidx][c];
    atomicAdd(
        &stats[(blockIdx.x & (NSLOT - 1)) * 256 + sidx * 128 + pair * 64 + c],
        v);
  }
}

// ---------------- BN apply + skip + relu, inline finalize -------------------
__global__ __launch_bounds__(256) void k_bn_apply(
    const float* __restrict__ V, const float* __restrict__ stats,
    const float* __restrict__ gamma, const float* __restrict__ beta,
    float invN, const float* __restrict__ skip, float* __restrict__ Y,
    int total4) {
  __shared__ float ssl[256];
  const int tid = threadIdx.x;
  if (tid < 128) {
    float s = 0.f, s2 = 0.f;
#pragma unroll
    for (int k = 0; k < NSLOT; ++k) {
      s += stats[k * 256 + tid];
      s2 += stats[k * 256 + 128 + tid];
    }
    float mean = s * invN;
    float var = s2 * invN - mean * mean;
    float sc = gamma[tid] * rsqrtf(var + 1e-5f);
    ssl[tid] = sc;
    ssl[128 + tid] = beta[tid] - mean * sc;
  }
  __syncthreads();
  for (int i = blockIdx.x * 256 + tid; i < total4; i += gridDim.x * 256) {
    const int c4 = i & 31;
    float4 v = ((const float4*)V)[i];
    float4 sc = *(const float4*)&ssl[c4 * 4];
    float4 sh = *(const float4*)&ssl[128 + c4 * 4];
    float4 s = ((const float4*)skip)[i];
    float4 y;
    y.x = fmaxf(fmaf(v.x, sc.x, sh.x) + s.x, 0.f);
    y.y = fmaxf(fmaf(v.y, sc.y, sh.y) + s.y, 0.f);
    y.z = fmaxf(fmaf(v.z, sc.z, sh.z) + s.z, 0.f);
    y.w = fmaxf(fmaf(v.w, sc.w, sh.w) + s.w, 0.f);
    ((float4*)Y)[i] = y;
  }
}

extern "C" void kernel_launch(void* const* d_in, const int* in_sizes, int n_in,
                              void* d_out, int out_size, void* d_ws,
                              size_t ws_size, hipStream_t stream) {
  const float* x = (const float*)d_in[0];
  const int* ei = (const int*)d_in[1];
  const float* W1 = (const float*)d_in[2];
  const float* a_src1 = (const float*)d_in[3];
  const float* a_dst1 = (const float*)d_in[4];
  // b1 cancels in BN
  const float* gamma1 = (const float*)d_in[6];
  const float* beta1 = (const float*)d_in[7];
  const float* W2 = (const float*)d_in[8];
  const float* a_src2 = (const float*)d_in[9];
  const float* a_dst2 = (const float*)d_in[10];
  // b2 cancels in BN
  const float* gamma2 = (const float*)d_in[12];
  const float* beta2 = (const float*)d_in[13];

  const int n = in_sizes[0] / 128;
  const int E = in_sizes[1] / 2;
  const int EP = E + n;
  const int NB = (n + 127) >> 7;  // dst buckets (<= MAXNB)
  const int EB = (E + 4095) / 4096;
  const float invN = 1.0f / (float)n;

  char* w = (char*)d_ws;
  const size_t szNC = (size_t)n * 128 * sizeof(float);
  unsigned* Hb = (unsigned*)w;  w += (size_t)n * 64 * sizeof(unsigned);
  float* Bagg = (float*)w;      w += szNC;
  float* as_ = (float*)w;       w += (size_t)n * 4 * sizeof(float);
  float* ad_ = (float*)w;       w += (size_t)n * 4 * sizeof(float);
  int* srcs = (int*)w;          w += (size_t)EP * sizeof(int);
  int* packed = (int*)w;        w += (size_t)E * sizeof(int);
  int* deg = (int*)w;           w += (size_t)n * sizeof(int);
  int* offs = (int*)w;          w += (size_t)n * sizeof(int);
  int* bstart = (int*)w;        w += (size_t)(NB + 1) * sizeof(int);
  int* bcur = (int*)w;          w += (size_t)NB * sizeof(int);
  uint4* Wf1 = (uint4*)w;       w += 2048 * sizeof(uint4);
  uint4* Wf2 = (uint4*)w;       w += 2048 * sizeof(uint4);
  // zero-region: bcnt + stats1 + stats2 + tile queues (single upfront memset)
  char* zreg = w;
  int* bcnt = (int*)w;          w += (size_t)NB * sizeof(int);
  float* stats1 = (float*)w;    w += NSLOT * 256 * sizeof(float);
  float* stats2 = (float*)w;    w += NSLOT * 256 * sizeof(float);
  int* qctr = (int*)w;          w += 4 * sizeof(int);  // [layer][pair]
  const size_t zbytes = (size_t)(w - zreg);

  hipMemsetAsync(zreg, 0, zbytes, stream);

  // ---- W fragment prep (one dispatch for both layers) ----
  k_wprep<<<16, 256, 0, stream>>>(W1, Wf1, W2, Wf2);

  // ---- CSR build (bucket binning; shared by both layers) ----
  k_hist<<<EB, 256, 0, stream>>>(ei, E, NB, bcnt);
  k_bprefix<<<1, 1024, 0, stream>>>(bcnt, NB, bstart, bcur);
  k_scatter<<<EB, 256, 0, stream>>>(ei, E, NB, bcur, packed);
  k_local<<<NB, 256, 0, stream>>>(packed, bstart, n, srcs, offs, deg);

  // ---- agg grid: 32 nodes x 1 head-pair per block, XCC-pinned queues ----
  const int ntiles = (n + 31) >> 5;
  const int nagg = 2 * ntiles;

  // ---- layer 1 ----
  k_gemm<<<(n + 63) / 64, 256, 0, stream>>>(x, Wf1, Hb, n, nullptr, nullptr,
                                            nullptr, invN, a_src1, a_dst1,
                                            as_, ad_);
  k_agg<<<nagg, 256, 0, stream>>>(offs, deg, srcs, (const uint4*)Hb, as_, ad_,
                                  Bagg, stats1, n, ntiles, qctr);

  // ---- layer 2 (BN1+ReLU folded into GEMM2; finalize inline) ----
  k_gemm<<<(n + 63) / 64, 256, 0, stream>>>(Bagg, Wf2, Hb, n, stats1, gamma1,
                                            beta1, invN, a_src2, a_dst2, as_,
                                            ad_);
  k_agg<<<nagg, 256, 0, stream>>>(offs, deg, srcs, (const uint4*)Hb, as_, ad_,
                                  Bagg, stats2, n, ntiles, qctr + 2);
  k_bn_apply<<<2048, 256, 0, stream>>>(Bagg, stats2, gamma2, beta2, invN, x,
                                       (float*)d_out, n * 32);
}

// Round 7
// 424.332 us; speedup vs baseline: 1.1880x; 1.1880x over previous
//
#include <hip/hip_runtime.h>

#define MAXNB 1024  // max dst-buckets (128 nodes each) -> supports n <= 131072
#define NSLOT 8     // BN stats spread (contention vs redundant-read tradeoff)

typedef __attribute__((ext_vector_type(8))) short bf8;    // 8 bf16 (4 VGPRs)
typedef __attribute__((ext_vector_type(4))) float f32x4;  // MFMA C/D

// pack two fp32 -> two bf16 (RNE) in one uint (a = low = even channel)
__device__ __forceinline__ unsigned pack_bf16x2(float a, float b) {
  unsigned ua = __float_as_uint(a);
  ua = (ua + 0x7fffu + ((ua >> 16) & 1u)) >> 16;
  unsigned ub = __float_as_uint(b);
  ub = (ub + 0x7fffu + ((ub >> 16) & 1u)) >> 16;
  return ua | (ub << 16);
}
// unpack low/high bf16 of a uint to f32
__device__ __forceinline__ float bl16(unsigned w) {
  return __uint_as_float(w << 16);
}
__device__ __forceinline__ float bh16(unsigned w) {
  return __uint_as_float(w & 0xffff0000u);
}

// ---- W prep: fp32 [128k][128c] -> bf16 B-fragments for 16x16x32 MFMA ------
// grid 16: blocks 0-7 -> W1/Wf1, blocks 8-15 -> W2/Wf2.
__global__ __launch_bounds__(256) void k_wprep(const float* __restrict__ W1,
                                               uint4* __restrict__ Wf1,
                                               const float* __restrict__ W2,
                                               uint4* __restrict__ Wf2) {
  const int half = blockIdx.x >> 3;
  const float* W = half ? W2 : W1;
  uint4* Wf = half ? Wf2 : Wf1;
  const int t = (blockIdx.x & 7) * 256 + threadIdx.x;  // 0..2047
  const int frag = t >> 6, lane = t & 63;
  const int ct = frag >> 2, kc = frag & 3;
  const int col = ct * 16 + (lane & 15);
  const int k0 = kc * 32 + (lane >> 4) * 8;
  unsigned p[4];
#pragma unroll
  for (int j = 0; j < 4; ++j)
    p[j] = pack_bf16x2(W[(k0 + 2 * j) * 128 + col],
                       W[(k0 + 2 * j + 1) * 128 + col]);
  Wf[t] = make_uint4(p[0], p[1], p[2], p[3]);
}

// ---- MFMA GEMM: H(bf16) = X[n,128] @ W[128,128], fused alpha dots ---------
// stats==null (layer 1): X is fp32.
// stats!=null (layer 2): X is bf16 (Bagg), and BN1-finalize + relu fold into
// the A-fragment load.
__global__ __launch_bounds__(256) void k_gemm(
    const float* __restrict__ X, const uint4* __restrict__ Wf,
    unsigned* __restrict__ Hb, int n, const float* __restrict__ stats,
    const float* __restrict__ gamma, const float* __restrict__ beta,
    float invN, const float* __restrict__ a_src,
    const float* __restrict__ a_dst, float* __restrict__ as_,
    float* __restrict__ ad_) {
  __shared__ float stag[64 * 132];  // 33792 B
  __shared__ float ssl[256];        // BN scale/shift
  const int tid = threadIdx.x;
  if (stats && tid < 128) {
    float s = 0.f, s2 = 0.f;
#pragma unroll
    for (int k = 0; k < NSLOT; ++k) {
      s += stats[k * 256 + tid];
      s2 += stats[k * 256 + 128 + tid];
    }
    float mean = s * invN;
    float var = s2 * invN - mean * mean;
    float sc = gamma[tid] * rsqrtf(var + 1e-5f);
    ssl[tid] = sc;
    ssl[128 + tid] = beta[tid] - mean * sc;
  }
  __syncthreads();

  const int w = tid >> 6, lane = tid & 63;
  const int q = lane >> 4, nl = lane & 15;
  const long row0 = (long)blockIdx.x * 64;
  long rowA = row0 + w * 16 + nl;
  if (rowA >= n) rowA = n - 1;  // clamp; stores are guarded

  bf8 a[4];
#pragma unroll
  for (int kc = 0; kc < 4; ++kc) {
    union { uint4 u; bf8 v; } cv;
    if (!stats) {  // layer 1: fp32 input
      const float* p = X + rowA * 128 + kc * 32 + q * 8;
      float4 v0 = *(const float4*)p;
      float4 v1 = *(const float4*)(p + 4);
      cv.u = make_uint4(pack_bf16x2(v0.x, v0.y), pack_bf16x2(v0.z, v0.w),
                        pack_bf16x2(v1.x, v1.y), pack_bf16x2(v1.z, v1.w));
    } else {  // layer 2: bf16 input + BN+ReLU fold
      const uint4 u =
          *(const uint4*)((const unsigned short*)X + rowA * 128 + kc * 32 +
                          q * 8);
      const int kb = kc * 32 + q * 8;
      float4 s0 = *(const float4*)&ssl[kb];
      float4 s1 = *(const float4*)&ssl[kb + 4];
      float4 h0 = *(const float4*)&ssl[128 + kb];
      float4 h1 = *(const float4*)&ssl[128 + kb + 4];
      float v0x = fmaxf(fmaf(bl16(u.x), s0.x, h0.x), 0.f);
      float v0y = fmaxf(fmaf(bh16(u.x), s0.y, h0.y), 0.f);
      float v0z = fmaxf(fmaf(bl16(u.y), s0.z, h0.z), 0.f);
      float v0w = fmaxf(fmaf(bh16(u.y), s0.w, h0.w), 0.f);
      float v1x = fmaxf(fmaf(bl16(u.z), s1.x, h1.x), 0.f);
      float v1y = fmaxf(fmaf(bh16(u.z), s1.y, h1.y), 0.f);
      float v1z = fmaxf(fmaf(bl16(u.w), s1.z, h1.z), 0.f);
      float v1w = fmaxf(fmaf(bh16(u.w), s1.w, h1.w), 0.f);
      cv.u = make_uint4(pack_bf16x2(v0x, v0y), pack_bf16x2(v0z, v0w),
                        pack_bf16x2(v1x, v1y), pack_bf16x2(v1z, v1w));
    }
    a[kc] = cv.v;
  }

  f32x4 acc[8];
#pragma unroll
  for (int ct = 0; ct < 8; ++ct) {
    f32x4 c = {0.f, 0.f, 0.f, 0.f};
#pragma unroll
    for (int kc = 0; kc < 4; ++kc) {
      union { uint4 u; bf8 v; } b;
      b.u = Wf[(ct * 4 + kc) * 64 + lane];
      c = __builtin_amdgcn_mfma_f32_16x16x32_bf16(a[kc], b.v, c, 0, 0, 0);
    }
    acc[ct] = c;
  }

  const int lr = w * 16 + q * 4;
#pragma unroll
  for (int ct = 0; ct < 8; ++ct)
#pragma unroll
    for (int r = 0; r < 4; ++r)
      stag[(lr + r) * 132 + ct * 16 + nl] = acc[ct][r];
  __syncthreads();

  {
    const int row = tid >> 2, seg = tid & 3;
    const long grow = row0 + row;
    if (grow < n) {
      float sp = 0.f, dp = 0.f;
      const float* p = &stag[row * 132 + seg * 32];
#pragma unroll
      for (int i = 0; i < 8; ++i) {
        float4 h4 = *(const float4*)(p + i * 4);
        float4 s4 = ((const float4*)a_src)[seg * 8 + i];
        float4 d4 = ((const float4*)a_dst)[seg * 8 + i];
        sp += h4.x * s4.x + h4.y * s4.y + h4.z * s4.z + h4.w * s4.w;
        dp += h4.x * d4.x + h4.y * d4.y + h4.z * d4.z + h4.w * d4.w;
        uint2 o;
        o.x = pack_bf16x2(h4.x, h4.y);
        o.y = pack_bf16x2(h4.z, h4.w);
        ((uint2*)Hb)[grow * 32 + seg * 8 + i] = o;
      }
      as_[grow * 4 + seg] = sp;
      ad_[grow * 4 + seg] = dp;
    }
  }
}

// ---------------- CSR build via dst-bucket binning --------------------------
__global__ __launch_bounds__(256) void k_hist(const int* __restrict__ ei,
                                              int E, int NB,
                                              int* __restrict__ bcnt) {
  __shared__ int hist[MAXNB];
  for (int i = threadIdx.x; i < NB; i += 256) hist[i] = 0;
  __syncthreads();
  const int e0 = blockIdx.x * 4096;
#pragma unroll
  for (int k = 0; k < 16; ++k) {
    int e = e0 + k * 256 + threadIdx.x;
    if (e < E) atomicAdd(&hist[ei[E + e] >> 7], 1);
  }
  __syncthreads();
  for (int i = threadIdx.x; i < NB; i += 256) {
    int c = hist[i];
    if (c) atomicAdd(&bcnt[i], c);
  }
}

__global__ __launch_bounds__(1024) void k_bprefix(const int* __restrict__ bcnt,
                                                  int NB,
                                                  int* __restrict__ bstart,
                                                  int* __restrict__ bcur) {
  __shared__ int sh[1024];
  const int t = threadIdx.x;
  int v = (t < NB) ? bcnt[t] : 0;
  sh[t] = v;
  __syncthreads();
  for (int off = 1; off < 1024; off <<= 1) {
    int u = (t >= off) ? sh[t - off] : 0;
    __syncthreads();
    sh[t] += u;
    __syncthreads();
  }
  if (t < NB) {
    int ex = sh[t] - v;
    bstart[t] = ex;
    bcur[t] = ex;
    if (t == NB - 1) bstart[NB] = sh[t];
  }
}

__global__ __launch_bounds__(256) void k_scatter(const int* __restrict__ ei,
                                                 int E, int NB,
                                                 int* __restrict__ bcur,
                                                 int* __restrict__ packed) {
  __shared__ int hist[MAXNB];
  __shared__ int hbase[MAXNB];
  for (int i = threadIdx.x; i < NB; i += 256) hist[i] = 0;
  __syncthreads();
  const int e0 = blockIdx.x * 4096;
  int myb[16], myv[16];
#pragma unroll
  for (int k = 0; k < 16; ++k) {
    int e = e0 + k * 256 + threadIdx.x;
    myb[k] = -1;
    myv[k] = 0;
    if (e < E) {
      int s = ei[e], d = ei[E + e];
      myb[k] = d >> 7;
      myv[k] = (s << 7) | (d & 127);
      atomicAdd(&hist[myb[k]], 1);
    }
  }
  __syncthreads();
  for (int i = threadIdx.x; i < NB; i += 256) {
    int c = hist[i];
    hbase[i] = c ? atomicAdd(&bcur[i], c) : 0;
    hist[i] = 0;
  }
  __syncthreads();
#pragma unroll
  for (int k = 0; k < 16; ++k) {
    if (myb[k] >= 0) {
      int p = hbase[myb[k]] + atomicAdd(&hist[myb[k]], 1);
      packed[p] = myv[k];
    }
  }
}

__global__ __launch_bounds__(256) void k_local(const int* __restrict__ packed,
                                               const int* __restrict__ bstart,
                                               int n, int* __restrict__ srcs,
                                               int* __restrict__ offs,
                                               int* __restrict__ deg) {
  const int b = blockIdx.x;
  const int node0 = b << 7;
  const int nn = min(128, n - node0);
  const int e0 = bstart[b], e1 = bstart[b + 1];
  __shared__ int dcnt[128], cur[128], scan[128];
  const int tid = threadIdx.x;
  if (tid < 128) dcnt[tid] = 0;
  __syncthreads();
  for (int i = e0 + tid; i < e1; i += 256)
    atomicAdd(&dcnt[packed[i] & 127], 1);
  __syncthreads();
  int v = 0;
  if (tid < 128) {
    v = (tid < nn) ? dcnt[tid] + 1 : 0;  // +1 = self-loop slot
    scan[tid] = v;
  }
  __syncthreads();
  for (int off = 1; off < 128; off <<= 1) {
    int u = 0;
    if (tid < 128 && tid >= off) u = scan[tid - off];
    __syncthreads();
    if (tid < 128) scan[tid] += u;
    __syncthreads();
  }
  if (tid < nn) {
    const int o = e0 + node0 + (scan[tid] - v);  // global CSR offset
    offs[node0 + tid] = o;
    deg[node0 + tid] = dcnt[tid];
    srcs[o] = node0 + tid;  // self-loop first
    cur[tid] = o + 1;
  }
  __syncthreads();
  for (int i = e0 + tid; i < e1; i += 256) {
    const int pv = packed[i];
    const int p = atomicAdd(&cur[pv & 127], 1);
    srcs[p] = pv >> 7;
  }
}

// ---------------- fused GAT aggregation + BN-stats accumulation -------------
// 16 thr/node, 4 nodes/wave, 16 nodes/block. VERBATIM round-1 structure
// (measured 87.4us, VGPR 32, occ 74% — the best of 6 structural variants;
// concurrency and sharding axes both exhausted with evidence r2-r6).
// Single change vs r1: output packed to bf16 (16B/thread store) — halves
// the out-write and the two downstream reads of it.
__global__ __launch_bounds__(256) void k_agg(
    const int* __restrict__ offs, const int* __restrict__ deg,
    const int* __restrict__ srcs, const uint4* __restrict__ Hb,
    const float* __restrict__ as_, const float* __restrict__ ad_,
    unsigned* __restrict__ out, float* __restrict__ stats, int n) {
  __shared__ float sblk[4][2][128];
  const int tid = threadIdx.x;
  const int node = blockIdx.x * 16 + (tid >> 4);
  const bool active = node < n;
  const int w = tid >> 6, lane = tid & 63;
  const int t = lane & 15;
  const int th = t >> 2;    // head of my channels
  const int j4 = lane & 3;  // my edge slot per chunk
  const int o0 = active ? offs[node] : 0;
  const int dg = active ? deg[node] + 1 : 1;  // + self-loop
  const float adv = active ? ad_[node * 4 + th] : 0.f;

  float den = 0.f;
  float acc[8];
#pragma unroll
  for (int i = 0; i < 8; ++i) acc[i] = 0.f;

// load slot J's (src, exp(leaky(logit))) — index clamped to the self-loop
// slot so the loads are always in-range / unconditional; weight zeroed.
#define LOADSE(J, S, EV)                               \
  {                                                    \
    const int j_ = (J);                                \
    S = srcs[o0 + (j_ < dg ? j_ : 0)];                 \
    float l_ = as_[S * 4 + th] + adv;                  \
    l_ = l_ >= 0.f ? l_ : 0.2f * l_;                   \
    EV = (j_ < dg) ? __expf(fminf(l_, 80.f)) : 0.f;    \
  }

// broadcast slot JJ's src id within the 16-lane node group, gather its row.
// swizzle BitMode: src_lane = (lane & 0x10) | JJ  (bit5 preserved by group)
#define GATHER(DST, SREG, JJ)                                            \
  {                                                                      \
    int ss_ = __builtin_amdgcn_ds_swizzle((SREG), ((JJ) << 5) | 0x10);   \
    DST = Hb[(long)ss_ * 16 + t];                                        \
  }

// weight broadcast: src_lane = (lane & 0x1C) | JJ (keep head, pick slot)
#define FMA8(HV, JJ, EREG)                                                 \
  {                                                                        \
    float wv_ = __uint_as_float(__builtin_amdgcn_ds_swizzle(               \
        __float_as_int(EREG), ((JJ) << 5) | 0x1C));                        \
    acc[0] = fmaf(wv_, __uint_as_float(HV.x << 16), acc[0]);               \
    acc[1] = fmaf(wv_, __uint_as_float(HV.x & 0xffff0000u), acc[1]);       \
    acc[2] = fmaf(wv_, __uint_as_float(HV.y << 16), acc[2]);               \
    acc[3] = fmaf(wv_, __uint_as_float(HV.y & 0xffff0000u), acc[3]);       \
    acc[4] = fmaf(wv_, __uint_as_float(HV.z << 16), acc[4]);               \
    acc[5] = fmaf(wv_, __uint_as_float(HV.z & 0xffff0000u), acc[5]);       \
    acc[6] = fmaf(wv_, __uint_as_float(HV.w << 16), acc[6]);               \
    acc[7] = fmaf(wv_, __uint_as_float(HV.w & 0xffff0000u), acc[7]);       \
  }

  // prologue: (s,e) for chunks 0 and 1; Hb rows for chunk 0
  int s_c, s_n, s_f;
  float e_c, e_n, e_f;
  LOADSE(j4, s_c, e_c);
  LOADSE(4 + j4, s_n, e_n);
  uint4 h0, h1, h2, h3;
  GATHER(h0, s_c, 0);
  GATHER(h1, s_c, 1);
  GATHER(h2, s_c, 2);
  GATHER(h3, s_c, 3);

  for (int base = 0; base < dg; base += 4) {
    // issue chunk base+8's logit chain (2-deep dependent load + exp)
    LOADSE(base + 8 + j4, s_f, e_f);
    // issue chunk base+4's row gathers (consumed next iteration)
    uint4 g0, g1, g2, g3;
    GATHER(g0, s_n, 0);
    GATHER(g1, s_n, 1);
    GATHER(g2, s_n, 2);
    GATHER(g3, s_n, 3);
    // consume current chunk (rows loaded one iteration ago)
    den += e_c;
    FMA8(h0, 0, e_c);
    FMA8(h1, 1, e_c);
    FMA8(h2, 2, e_c);
    FMA8(h3, 3, e_c);
    // rotate pipeline state
    s_c = s_n; e_c = e_n;
    s_n = s_f; e_n = e_f;
    h0 = g0; h1 = g1; h2 = g2; h3 = g3;
  }
#undef LOADSE
#undef GATHER
#undef FMA8

  den += __shfl_xor(den, 1, 64);
  den += __shfl_xor(den, 2, 64);
  const float invden = 1.f / (den + 1e-16f);
  float sums[8], sqs[8];
#pragma unroll
  for (int i = 0; i < 8; ++i) {
    float v = acc[i] * invden;
    acc[i] = v;
    sums[i] = v;
    sqs[i] = v * v;
  }
  if (active) {  // bf16 output: 16B/thread (was 32B fp32)
    uint4 o;
    o.x = pack_bf16x2(acc[0], acc[1]);
    o.y = pack_bf16x2(acc[2], acc[3]);
    o.z = pack_bf16x2(acc[4], acc[5]);
    o.w = pack_bf16x2(acc[6], acc[7]);
    ((uint4*)out)[(long)node * 16 + t] = o;
  }
  // wave reduce over the wave's 4 nodes (lane>>4 groups)
#pragma unroll
  for (int off = 16; off <= 32; off <<= 1) {
#pragma unroll
    for (int i = 0; i < 8; ++i) {
      sums[i] += __shfl_xor(sums[i], off, 64);
      sqs[i] += __shfl_xor(sqs[i], off, 64);
    }
  }
  if (lane < 16) {
#pragma unroll
    for (int i = 0; i < 8; ++i) {
      sblk[w][0][lane * 8 + i] = sums[i];
      sblk[w][1][lane * 8 + i] = sqs[i];
    }
  }
  __syncthreads();
  {
    const int c = tid & 127, sidx = tid >> 7;
    float v = sblk[0][sidx][c] + sblk[1][sidx][c] + sblk[2][sidx][c] +
              sblk[3][sidx][c];
    atomicAdd(&stats[(blockIdx.x & (NSLOT - 1)) * 256 + sidx * 128 + c], v);
  }
}

// ---------------- BN apply + skip + relu, inline finalize -------------------
// V is bf16 (n x 128); skip is fp32 x; Y is fp32 out.
__global__ __launch_bounds__(256) void k_bn_apply(
    const uint4* __restrict__ V, const float* __restrict__ stats,
    const float* __restrict__ gamma, const float* __restrict__ beta,
    float invN, const float* __restrict__ skip, float* __restrict__ Y,
    int total8) {
  __shared__ float ssl[256];
  const int tid = threadIdx.x;
  if (tid < 128) {
    float s = 0.f, s2 = 0.f;
#pragma unroll
    for (int k = 0; k < NSLOT; ++k) {
      s += stats[k * 256 + tid];
      s2 += stats[k * 256 + 128 + tid];
    }
    float mean = s * invN;
    float var = s2 * invN - mean * mean;
    float sc = gamma[tid] * rsqrtf(var + 1e-5f);
    ssl[tid] = sc;
    ssl[128 + tid] = beta[tid] - mean * sc;
  }
  __syncthreads();
  for (int i = blockIdx.x * 256 + tid; i < total8; i += gridDim.x * 256) {
    const int c8 = (i & 15) * 8;
    uint4 u = V[i];
    float4 sc0 = *(const float4*)&ssl[c8];
    float4 sc1 = *(const float4*)&ssl[c8 + 4];
    float4 sh0 = *(const float4*)&ssl[128 + c8];
    float4 sh1 = *(const float4*)&ssl[128 + c8 + 4];
    float4 s0 = ((const float4*)skip)[i * 2];
    float4 s1 = ((const float4*)skip)[i * 2 + 1];
    float4 y0, y1;
    y0.x = fmaxf(fmaf(bl16(u.x), sc0.x, sh0.x) + s0.x, 0.f);
    y0.y = fmaxf(fmaf(bh16(u.x), sc0.y, sh0.y) + s0.y, 0.f);
    y0.z = fmaxf(fmaf(bl16(u.y), sc0.z, sh0.z) + s0.z, 0.f);
    y0.w = fmaxf(fmaf(bh16(u.y), sc0.w, sh0.w) + s0.w, 0.f);
    y1.x = fmaxf(fmaf(bl16(u.z), sc1.x, sh1.x) + s1.x, 0.f);
    y1.y = fmaxf(fmaf(bh16(u.z), sc1.y, sh1.y) + s1.y, 0.f);
    y1.z = fmaxf(fmaf(bl16(u.w), sc1.z, sh1.z) + s1.z, 0.f);
    y1.w = fmaxf(fmaf(bh16(u.w), sc1.w, sh1.w) + s1.w, 0.f);
    ((float4*)Y)[i * 2] = y0;
    ((float4*)Y)[i * 2 + 1] = y1;
  }
}

extern "C" void kernel_launch(void* const* d_in, const int* in_sizes, int n_in,
                              void* d_out, int out_size, void* d_ws,
                              size_t ws_size, hipStream_t stream) {
  const float* x = (const float*)d_in[0];
  const int* ei = (const int*)d_in[1];
  const float* W1 = (const float*)d_in[2];
  const float* a_src1 = (const float*)d_in[3];
  const float* a_dst1 = (const float*)d_in[4];
  // b1 cancels in BN
  const float* gamma1 = (const float*)d_in[6];
  const float* beta1 = (const float*)d_in[7];
  const float* W2 = (const float*)d_in[8];
  const float* a_src2 = (const float*)d_in[9];
  const float* a_dst2 = (const float*)d_in[10];
  // b2 cancels in BN
  const float* gamma2 = (const float*)d_in[12];
  const float* beta2 = (const float*)d_in[13];

  const int n = in_sizes[0] / 128;
  const int E = in_sizes[1] / 2;
  const int EP = E + n;
  const int NB = (n + 127) >> 7;  // dst buckets (<= MAXNB)
  const int EB = (E + 4095) / 4096;
  const float invN = 1.0f / (float)n;

  char* w = (char*)d_ws;
  unsigned* Hb = (unsigned*)w;  w += (size_t)n * 64 * sizeof(unsigned);
  unsigned* Bagg = (unsigned*)w; w += (size_t)n * 64 * sizeof(unsigned);
  float* as_ = (float*)w;       w += (size_t)n * 4 * sizeof(float);
  float* ad_ = (float*)w;       w += (size_t)n * 4 * sizeof(float);
  int* srcs = (int*)w;          w += (size_t)EP * sizeof(int);
  int* packed = (int*)w;        w += (size_t)E * sizeof(int);
  int* deg = (int*)w;           w += (size_t)n * sizeof(int);
  int* offs = (int*)w;          w += (size_t)n * sizeof(int);
  int* bstart = (int*)w;        w += (size_t)(NB + 1) * sizeof(int);
  int* bcur = (int*)w;          w += (size_t)NB * sizeof(int);
  uint4* Wf1 = (uint4*)w;       w += 2048 * sizeof(uint4);
  uint4* Wf2 = (uint4*)w;       w += 2048 * sizeof(uint4);
  // zero-region: bcnt + stats1 + stats2 (single upfront memset)
  char* zreg = w;
  int* bcnt = (int*)w;          w += (size_t)NB * sizeof(int);
  float* stats1 = (float*)w;    w += NSLOT * 256 * sizeof(float);
  float* stats2 = (float*)w;    w += NSLOT * 256 * sizeof(float);
  const size_t zbytes = (size_t)(w - zreg);

  hipMemsetAsync(zreg, 0, zbytes, stream);

  // ---- W fragment prep (one dispatch for both layers) ----
  k_wprep<<<16, 256, 0, stream>>>(W1, Wf1, W2, Wf2);

  // ---- CSR build (bucket binning; shared by both layers) ----
  k_hist<<<EB, 256, 0, stream>>>(ei, E, NB, bcnt);
  k_bprefix<<<1, 1024, 0, stream>>>(bcnt, NB, bstart, bcur);
  k_scatter<<<EB, 256, 0, stream>>>(ei, E, NB, bcur, packed);
  k_local<<<NB, 256, 0, stream>>>(packed, bstart, n, srcs, offs, deg);

  // ---- layer 1 ----
  k_gemm<<<(n + 63) / 64, 256, 0, stream>>>(x, Wf1, Hb, n, nullptr, nullptr,
                                            nullptr, invN, a_src1, a_dst1,
                                            as_, ad_);
  k_agg<<<(n + 15) / 16, 256, 0, stream>>>(offs, deg, srcs, (const uint4*)Hb,
                                           as_, ad_, Bagg, stats1, n);

  // ---- layer 2 (BN1+ReLU folded into GEMM2; bf16 Bagg input) ----
  k_gemm<<<(n + 63) / 64, 256, 0, stream>>>((const float*)Bagg, Wf2, Hb, n,
                                            stats1, gamma1, beta1, invN,
                                            a_src2, a_dst2, as_, ad_);
  k_agg<<<(n + 15) / 16, 256, 0, stream>>>(offs, deg, srcs, (const uint4*)Hb,
                                           as_, ad_, Bagg, stats2, n);
  k_bn_apply<<<2048, 256, 0, stream>>>((const uint4*)Bagg, stats2, gamma2,
                                       beta2, invN, x, (float*)d_out, n * 16);
}